// Round 1
// baseline (727.845 us; speedup 1.0000x reference)
//
#include <hip/hip_runtime.h>
#include <stdint.h>
#include <stddef.h>

// BAMM attention block, MI355X.  B=8 C=512 Ck=128 H=W=128 DS=4 -> h=w=32 N=1024.
#define Bn   8
#define Cn   512
#define CKn  128
#define Hn   128
#define Nn   1024
#define HPn  32

typedef float f32x4 __attribute__((ext_vector_type(4)));
typedef short bf16x8 __attribute__((ext_vector_type(8)));

// ---------- helpers ----------
__device__ __forceinline__ uint16_t f2b(float f) {
  // fp32 -> bf16 RNE (inputs finite)
  uint32_t x = __float_as_uint(f);
  uint32_t r = (x + 0x7FFFu + ((x >> 16) & 1u)) >> 16;
  return (uint16_t)r;
}

__device__ __forceinline__ void gld_lds16(const uint16_t* g, short* lds_base, int lane) {
#if __has_builtin(__builtin_amdgcn_global_load_lds)
  // HW writes lane l's 16B at lds_base + l*16 (wave-uniform base)
  __builtin_amdgcn_global_load_lds(
      (const __attribute__((address_space(1))) void*)g,
      (__attribute__((address_space(3))) void*)lds_base, 16, 0, 0);
#else
  *(bf16x8*)(lds_base + lane * 8) = *(const bf16x8*)g;
#endif
}

// stage a 128x32 bf16 tile from g (row stride ld elems) into lds linear [128][32]
__device__ __forceinline__ void stage128x32(const uint16_t* __restrict__ g, int ld,
                                            short* lds, int wave, int lane) {
  const int rin = lane >> 2;   // row within 16-row chunk
  const int cc  = lane & 3;    // 16B column chunk
#pragma unroll
  for (int s = 0; s < 2; ++s) {
    int i = wave * 2 + s;      // instr 0..7, covers rows i*16..i*16+15
    gld_lds16(g + (size_t)(i * 16 + rin) * ld + cc * 8, lds + i * 512, lane);
  }
}

// NT GEMM core: A [128 rows][K] row-major (tile base), Bt [128 rows][K] row-major.
// acc[i][j] is the 16x16 frag at rows wm*64+i*16, cols wn*64+j*16.
__device__ __forceinline__ void gemm_core(const uint16_t* __restrict__ A,
                                          const uint16_t* __restrict__ Bt,
                                          int ld, int K,
                                          short* As, short* Bs,
                                          f32x4 acc[4][4]) {
  const int tid  = threadIdx.x;
  const int lane = tid & 63;
  const int wave = tid >> 6;
  const int wm = wave >> 1, wn = wave & 1;
  const int quad = lane >> 4, l16 = lane & 15;
  for (int kt = 0; kt < K; kt += 32) {
    __syncthreads();                       // protect LDS from prev-iter readers
    stage128x32(A + kt, ld, As, wave, lane);
    stage128x32(Bt + kt, ld, Bs, wave, lane);
    __syncthreads();                       // drains vmcnt (global_load_lds) too
    bf16x8 af[4], bfr[4];
#pragma unroll
    for (int i = 0; i < 4; ++i) {
      af[i]  = *(const bf16x8*)(As + (wm * 64 + i * 16 + l16) * 32 + quad * 8);
      bfr[i] = *(const bf16x8*)(Bs + (wn * 64 + i * 16 + l16) * 32 + quad * 8);
    }
#pragma unroll
    for (int i = 0; i < 4; ++i)
#pragma unroll
      for (int j = 0; j < 4; ++j)
        acc[i][j] = __builtin_amdgcn_mfma_f32_16x16x32_bf16(af[i], bfr[j], acc[i][j], 0, 0, 0);
  }
}

#define EPI_VARS \
  const int lane = threadIdx.x & 63; const int wave = threadIdx.x >> 6; \
  const int wm = wave >> 1, wn = wave & 1; \
  const int quad = lane >> 4, l16 = lane & 15;

// ---------- kernel 1: weights fp32 -> bf16 ----------
__global__ __launch_bounds__(256) void wconv_kernel(
    const float* __restrict__ Wq, const float* __restrict__ Wk, const float* __restrict__ Wv,
    uint16_t* __restrict__ Wqb, uint16_t* __restrict__ Wkb, uint16_t* __restrict__ Wvb) {
  int i = blockIdx.x * 256 + threadIdx.x;         // grid = 1024 blocks -> i < 262144
  if (i < CKn * Cn) { Wqb[i] = f2b(Wq[i]); Wkb[i] = f2b(Wk[i]); }
  Wvb[i] = f2b(Wv[i]);
}

// ---------- kernel 2: 4x4 avg-pool + transpose to [b][n][c] bf16 ----------
// grid (16 cblk, 32 ph, 16 = b*2+src), block 1024 = 32c x 32pw
__global__ __launch_bounds__(1024) void pool_kernel(
    const float* __restrict__ input, const float* __restrict__ c2,
    uint16_t* __restrict__ xT, uint16_t* __restrict__ yT) {
  const int cblk = blockIdx.x, ph = blockIdx.y;
  const int b = blockIdx.z >> 1, src = blockIdx.z & 1;
  const float* in = src ? c2 : input;
  uint16_t* out = src ? yT : xT;
  const int tw = threadIdx.x & 31, tc = threadIdx.x >> 5;
  const int c = cblk * 32 + tc;
  const float* p = in + (((size_t)(b * Cn + c) * Hn) + ph * 4) * Hn + tw * 4;
  float s = 0.f;
#pragma unroll
  for (int r = 0; r < 4; ++r) {
    float4 t = *(const float4*)(p + (size_t)r * Hn);
    s += t.x + t.y + t.z + t.w;
  }
  __shared__ float tile[32][33];
  tile[tw][tc] = s * 0.0625f;
  __syncthreads();
  const int tn = threadIdx.x >> 5, tcc = threadIdx.x & 31;   // now c fastest
  out[((size_t)b * Nn + ph * 32 + tn) * Cn + cblk * 32 + tcc] = f2b(tile[tn][tcc]);
}

// ---------- kernel 3: qkv GEMMs (NT).  q,k stored transposed [n][o]; v natural [c][n] ----------
// grid 384 = 8 batches * (8 q + 8 k + 32 v) blocks
__global__ __launch_bounds__(256) void qkv_kernel(
    const uint16_t* __restrict__ Wqb, const uint16_t* __restrict__ Wkb, const uint16_t* __restrict__ Wvb,
    const float* __restrict__ bq, const float* __restrict__ bk, const float* __restrict__ bv,
    const uint16_t* __restrict__ xT, const uint16_t* __restrict__ yT,
    uint16_t* __restrict__ qT, uint16_t* __restrict__ kT, uint16_t* __restrict__ vm) {
  __shared__ short As[4096], Bs[4096];
  const int bx = blockIdx.x;
  const int b = bx / 48, r = bx % 48;
  const uint16_t *A, *Bt; const float* bias; int mt, nt, op;
  if (r < 8)       { op = 0; mt = 0;            nt = r;            A = Wqb; Bt = xT; bias = bq; }
  else if (r < 16) { op = 1; mt = 0;            nt = r - 8;        A = Wkb; Bt = yT; bias = bk; }
  else             { op = 2; mt = (r - 16) >> 3; nt = (r - 16) & 7; A = Wvb; Bt = yT; bias = bv; }
  A  += (size_t)mt * 128 * Cn;
  Bt += (size_t)b * Nn * Cn + (size_t)nt * 128 * Cn;
  f32x4 acc[4][4];
#pragma unroll
  for (int i = 0; i < 4; ++i)
#pragma unroll
    for (int j = 0; j < 4; ++j) acc[i][j] = (f32x4)0.f;
  gemm_core(A, Bt, Cn, Cn, As, Bs, acc);
  EPI_VARS;
#pragma unroll
  for (int i = 0; i < 4; ++i)
#pragma unroll
    for (int j = 0; j < 4; ++j)
#pragma unroll
      for (int rg = 0; rg < 4; ++rg) {
        int m = mt * 128 + wm * 64 + i * 16 + quad * 4 + rg;   // out-channel
        int n = nt * 128 + wn * 64 + j * 16 + l16;             // pixel
        float val = acc[i][j][rg] + bias[m];
        if (op == 2) vm[(size_t)b * Cn * Nn + (size_t)m * Nn + n] = f2b(val);
        else {
          uint16_t* dst = (op == 0) ? qT : kT;
          dst[(size_t)b * Nn * CKn + (size_t)n * CKn + m] = f2b(val);   // transposed store
        }
      }
}

// ---------- kernel 4: energy = qT * kT^T * scale (NT, K=128) -> fp32 ----------
// grid 512 = 8 b * 8 mt * 8 nt
__global__ __launch_bounds__(256) void energy_kernel(
    const uint16_t* __restrict__ qT, const uint16_t* __restrict__ kT,
    float* __restrict__ energy) {
  __shared__ short As[4096], Bs[4096];
  const int bx = blockIdx.x;
  const int b = bx >> 6, r = bx & 63, mt = r >> 3, nt = r & 7;
  const uint16_t* A  = qT + (size_t)b * Nn * CKn + (size_t)mt * 128 * CKn;
  const uint16_t* Bt = kT + (size_t)b * Nn * CKn + (size_t)nt * 128 * CKn;
  f32x4 acc[4][4];
#pragma unroll
  for (int i = 0; i < 4; ++i)
#pragma unroll
    for (int j = 0; j < 4; ++j) acc[i][j] = (f32x4)0.f;
  gemm_core(A, Bt, CKn, CKn, As, Bs, acc);
  EPI_VARS;
  const float scale = 0.08838834764831845f;  // 128^-0.5
#pragma unroll
  for (int i = 0; i < 4; ++i)
#pragma unroll
    for (int j = 0; j < 4; ++j)
#pragma unroll
      for (int rg = 0; rg < 4; ++rg) {
        int n = mt * 128 + wm * 64 + i * 16 + quad * 4 + rg;   // energy row
        int m = nt * 128 + wn * 64 + j * 16 + l16;             // energy col
        energy[(size_t)b * Nn * Nn + (size_t)n * Nn + m] = acc[i][j][rg] * scale;
      }
}

// ---------- kernel 5: row softmax, fp32 -> bf16 attn ----------
// grid 8192 rows, 256 threads (4 elems each)
__global__ __launch_bounds__(256) void softmax_kernel(
    const float* __restrict__ energy, uint16_t* __restrict__ attn) {
  const size_t row = blockIdx.x;
  const float* e = energy + row * Nn;
  const int t = threadIdx.x;
  float v0[4];
  float mx = -3.4e38f;
#pragma unroll
  for (int i = 0; i < 4; ++i) { v0[i] = e[t + i * 256]; mx = fmaxf(mx, v0[i]); }
#pragma unroll
  for (int off = 32; off; off >>= 1) mx = fmaxf(mx, __shfl_xor(mx, off, 64));
  __shared__ float redm[4], reds[4];
  const int lane = t & 63, wave = t >> 6;
  if (lane == 0) redm[wave] = mx;
  __syncthreads();
  mx = fmaxf(fmaxf(redm[0], redm[1]), fmaxf(redm[2], redm[3]));
  float s = 0.f;
#pragma unroll
  for (int i = 0; i < 4; ++i) { v0[i] = __expf(v0[i] - mx); s += v0[i]; }
#pragma unroll
  for (int off = 32; off; off >>= 1) s += __shfl_xor(s, off, 64);
  if (lane == 0) reds[wave] = s;
  __syncthreads();
  s = reds[0] + reds[1] + reds[2] + reds[3];
  const float inv = 1.f / s;
#pragma unroll
  for (int i = 0; i < 4; ++i) attn[row * Nn + t + i * 256] = f2b(v0[i] * inv);
}

// ---------- kernel 6: out = v * attn^T (NT, K=1024), fused 4x nearest-upsample + c2 ----------
// grid 256 = 8 b * 4 mt * 8 nt
__global__ __launch_bounds__(256) void out_kernel(
    const uint16_t* __restrict__ vm, const uint16_t* __restrict__ attn,
    const float* __restrict__ c2, float* __restrict__ out) {
  __shared__ short As[4096], Bs[4096];
  const int bx = blockIdx.x;
  const int b = bx >> 5, r = bx & 31, mt = r >> 3, nt = r & 7;
  const uint16_t* A  = vm   + (size_t)b * Cn * Nn + (size_t)mt * 128 * Nn;
  const uint16_t* Bt = attn + (size_t)b * Nn * Nn + (size_t)nt * 128 * Nn;
  f32x4 acc[4][4];
#pragma unroll
  for (int i = 0; i < 4; ++i)
#pragma unroll
    for (int j = 0; j < 4; ++j) acc[i][j] = (f32x4)0.f;
  gemm_core(A, Bt, Nn, Nn, As, Bs, acc);
  EPI_VARS;
#pragma unroll
  for (int i = 0; i < 4; ++i)
#pragma unroll
    for (int j = 0; j < 4; ++j)
#pragma unroll
      for (int rg = 0; rg < 4; ++rg) {
        int c = mt * 128 + wm * 64 + i * 16 + quad * 4 + rg;
        int n = nt * 128 + wn * 64 + j * 16 + l16;
        int ph = n >> 5, pw = n & 31;
        float val = acc[i][j][rg];
        size_t base = (((size_t)(b * Cn + c) * Hn) + ph * 4) * Hn + pw * 4;
#pragma unroll
        for (int rr = 0; rr < 4; ++rr) {
          float4 t4 = *(const float4*)(c2 + base + (size_t)rr * Hn);
          t4.x += val; t4.y += val; t4.z += val; t4.w += val;
          *(float4*)(out + base + (size_t)rr * Hn) = t4;
        }
      }
}

// ---------- launch ----------
extern "C" void kernel_launch(void* const* d_in, const int* in_sizes, int n_in,
                              void* d_out, int out_size, void* d_ws, size_t ws_size,
                              hipStream_t stream) {
  const float* input = (const float*)d_in[0];
  const float* c2    = (const float*)d_in[1];
  const float* Wq    = (const float*)d_in[2];
  const float* bq    = (const float*)d_in[3];
  const float* Wk    = (const float*)d_in[4];
  const float* bk    = (const float*)d_in[5];
  const float* Wv    = (const float*)d_in[6];
  const float* bv    = (const float*)d_in[7];
  float* out = (float*)d_out;
  uint8_t* ws = (uint8_t*)d_ws;

  // workspace layout (bytes), all offsets 256-aligned
  uint16_t* xT   = (uint16_t*)(ws + 0);            //  8 MB: [8][1024][512]
  uint16_t* yT   = (uint16_t*)(ws + 8388608);      //  8 MB
  uint16_t* Wqb  = (uint16_t*)(ws + 16777216);     // 128 KB
  uint16_t* Wkb  = (uint16_t*)(ws + 16908288);     // 128 KB
  uint16_t* Wvb  = (uint16_t*)(ws + 17039360);     // 512 KB
  uint16_t* qT   = (uint16_t*)(ws + 17563648);     //   2 MB: [8][1024][128]
  uint16_t* kT   = (uint16_t*)(ws + 19660800);     //   2 MB
  uint16_t* vm   = (uint16_t*)(ws + 21757952);     //   8 MB: [8][512][1024]
  float*    eng  = (float*)   (ws + 30146560);     //  32 MB: [8][1024][1024] fp32
  uint16_t* attn = (uint16_t*)(ws + 63700992);     //  16 MB: [8][1024][1024] bf16
  // total 80,478,208 bytes

  hipLaunchKernelGGL(wconv_kernel, dim3(1024), dim3(256), 0, stream,
                     Wq, Wk, Wv, Wqb, Wkb, Wvb);
  hipLaunchKernelGGL(pool_kernel, dim3(16, 32, 16), dim3(1024), 0, stream,
                     input, c2, xT, yT);
  hipLaunchKernelGGL(qkv_kernel, dim3(384), dim3(256), 0, stream,
                     Wqb, Wkb, Wvb, bq, bk, bv, xT, yT, qT, kT, vm);
  hipLaunchKernelGGL(energy_kernel, dim3(512), dim3(256), 0, stream, qT, kT, eng);
  hipLaunchKernelGGL(softmax_kernel, dim3(8192), dim3(256), 0, stream, eng, attn);
  hipLaunchKernelGGL(out_kernel, dim3(256), dim3(256), 0, stream, vm, attn, c2, out);
}

// Round 2
// 705.541 us; speedup vs baseline: 1.0316x; 1.0316x over previous
//
#include <hip/hip_runtime.h>
#include <stdint.h>
#include <stddef.h>

// BAMM attention block, MI355X.  B=8 C=512 Ck=128 H=W=128 DS=4 -> h=w=32 N=1024.
#define Bn   8
#define Cn   512
#define CKn  128
#define Hn   128
#define Nn   1024

typedef float f32x4 __attribute__((ext_vector_type(4)));
typedef short bf16x8 __attribute__((ext_vector_type(8)));

// ---------- helpers ----------
__device__ __forceinline__ uint16_t f2b(float f) {
  uint32_t x = __float_as_uint(f);
  uint32_t r = (x + 0x7FFFu + ((x >> 16) & 1u)) >> 16;
  return (uint16_t)r;
}

__device__ __forceinline__ void gld_lds16(const uint16_t* g, short* lds_base, int lane) {
#if __has_builtin(__builtin_amdgcn_global_load_lds)
  __builtin_amdgcn_global_load_lds(
      (const __attribute__((address_space(1))) void*)g,
      (__attribute__((address_space(3))) void*)lds_base, 16, 0, 0);
#else
  *(bf16x8*)(lds_base + lane * 8) = *(const bf16x8*)g;
#endif
}

// ---------- 64x128 NT GEMM core ----------
// A [64 rows][K] (lda), Bt [128 rows][K] (ldb), both k-contiguous.
// 4 waves: wave w owns output rows w*16..w*16+15, all 128 cols.
// acc[j][rg] -> row w*16 + quad*4 + rg, col j*16 + l16.
__device__ __forceinline__ void gemm64x128(const uint16_t* __restrict__ A,
                                           const uint16_t* __restrict__ Bt,
                                           int lda, int ldb, int K,
                                           short* As, short* Bs, f32x4 acc[8]) {
  const int tid  = threadIdx.x;
  const int lane = tid & 63;
  const int wave = tid >> 6;
  const int quad = lane >> 4, l16 = lane & 15;
  const int rin  = lane >> 2, cc = lane & 3;   // staging: row-in-16, 16B col chunk
  for (int kt = 0; kt < K; kt += 32) {
    __syncthreads();                            // prev-iter readers done
    // A tile 64x32: 4 instrs (1/wave)
    gld_lds16(A + (size_t)(wave * 16 + rin) * lda + kt + cc * 8, As + wave * 512, lane);
    // B tile 128x32: 8 instrs (2/wave)
    gld_lds16(Bt + (size_t)(wave * 32 + rin) * ldb + kt + cc * 8, Bs + wave * 1024, lane);
    gld_lds16(Bt + (size_t)(wave * 32 + 16 + rin) * ldb + kt + cc * 8, Bs + wave * 1024 + 512, lane);
    __syncthreads();                            // drains vmcnt -> LDS visible
    bf16x8 af = *(const bf16x8*)(As + (wave * 16 + l16) * 32 + quad * 8);
#pragma unroll
    for (int j = 0; j < 8; ++j) {
      bf16x8 bfr = *(const bf16x8*)(Bs + (j * 16 + l16) * 32 + quad * 8);
      acc[j] = __builtin_amdgcn_mfma_f32_16x16x32_bf16(af, bfr, acc[j], 0, 0, 0);
    }
  }
}

#define EPI_VARS \
  const int lane = threadIdx.x & 63; const int wave = threadIdx.x >> 6; \
  const int quad = lane >> 4, l16 = lane & 15;

// ---------- kernel 1: weights fp32 -> bf16 ----------
__global__ __launch_bounds__(256) void wconv_kernel(
    const float* __restrict__ Wq, const float* __restrict__ Wk, const float* __restrict__ Wv,
    uint16_t* __restrict__ Wqb, uint16_t* __restrict__ Wkb, uint16_t* __restrict__ Wvb) {
  int i = blockIdx.x * 256 + threadIdx.x;
  if (i < CKn * Cn) { Wqb[i] = f2b(Wq[i]); Wkb[i] = f2b(Wk[i]); }
  Wvb[i] = f2b(Wv[i]);
}

// ---------- kernel 2: 4x4 avg-pool + transpose to [b][n][c] bf16 ----------
__global__ __launch_bounds__(1024) void pool_kernel(
    const float* __restrict__ input, const float* __restrict__ c2,
    uint16_t* __restrict__ xT, uint16_t* __restrict__ yT) {
  const int cblk = blockIdx.x, ph = blockIdx.y;
  const int b = blockIdx.z >> 1, src = blockIdx.z & 1;
  const float* in = src ? c2 : input;
  uint16_t* out = src ? yT : xT;
  const int tw = threadIdx.x & 31, tc = threadIdx.x >> 5;
  const int c = cblk * 32 + tc;
  const float* p = in + (((size_t)(b * Cn + c) * Hn) + ph * 4) * Hn + tw * 4;
  float s = 0.f;
#pragma unroll
  for (int r = 0; r < 4; ++r) {
    float4 t = *(const float4*)(p + (size_t)r * Hn);
    s += t.x + t.y + t.z + t.w;
  }
  __shared__ float tile[32][33];
  tile[tw][tc] = s * 0.0625f;
  __syncthreads();
  const int tn = threadIdx.x >> 5, tcc = threadIdx.x & 31;
  out[((size_t)b * Nn + ph * 32 + tn) * Cn + cblk * 32 + tcc] = f2b(tile[tn][tcc]);
}

// ---------- kernel 3: qkv GEMMs (NT, 64x128 tiles) ----------
// grid 768 = 8 b * 12 mt * 8 nt.  mt 0-1: q, 2-3: k, 4-11: v
__global__ __launch_bounds__(256) void qkv_kernel(
    const uint16_t* __restrict__ Wqb, const uint16_t* __restrict__ Wkb, const uint16_t* __restrict__ Wvb,
    const float* __restrict__ bq, const float* __restrict__ bk, const float* __restrict__ bv,
    const uint16_t* __restrict__ xT, const uint16_t* __restrict__ yT,
    uint16_t* __restrict__ qT, uint16_t* __restrict__ kT, uint16_t* __restrict__ vm) {
  __shared__ short As[2048], Bs[4096];
  const int bx = blockIdx.x;
  const int b = bx / 96, r = bx % 96;
  const int mt = r >> 3, nt = r & 7;
  int op, mbase; const uint16_t* A; const float* bias;
  if (mt < 2)      { op = 0; mbase = mt * 64;       A = Wqb + (size_t)mbase * Cn; bias = bq; }
  else if (mt < 4) { op = 1; mbase = (mt - 2) * 64; A = Wkb + (size_t)mbase * Cn; bias = bk; }
  else             { op = 2; mbase = (mt - 4) * 64; A = Wvb + (size_t)mbase * Cn; bias = bv; }
  const uint16_t* Bt = ((op == 0) ? xT : yT) + (size_t)b * Nn * Cn + (size_t)nt * 128 * Cn;
  f32x4 acc[8];
#pragma unroll
  for (int j = 0; j < 8; ++j) acc[j] = (f32x4)0.f;
  gemm64x128(A, Bt, Cn, Cn, Cn, As, Bs, acc);
  EPI_VARS;
#pragma unroll
  for (int j = 0; j < 8; ++j)
#pragma unroll
    for (int rg = 0; rg < 4; ++rg) {
      int m = mbase + wave * 16 + quad * 4 + rg;
      int n = nt * 128 + j * 16 + l16;
      float val = acc[j][rg] + bias[m];
      if (op == 2) vm[(size_t)b * Cn * Nn + (size_t)m * Nn + n] = f2b(val);
      else {
        uint16_t* dst = (op == 0) ? qT : kT;
        dst[(size_t)b * Nn * CKn + (size_t)n * CKn + m] = f2b(val);
      }
    }
}

// ---------- kernel 4: energy = q^T k * scale (NT, K=128) -> fp32 ----------
// grid 1024 = 8 b * 16 mt * 8 nt
__global__ __launch_bounds__(256) void energy_kernel(
    const uint16_t* __restrict__ qT, const uint16_t* __restrict__ kT,
    float* __restrict__ energy) {
  __shared__ short As[2048], Bs[4096];
  const int bx = blockIdx.x;
  const int b = bx >> 7, r = bx & 127, mt = r >> 3, nt = r & 7;
  const uint16_t* A  = qT + (size_t)b * Nn * CKn + (size_t)mt * 64 * CKn;
  const uint16_t* Bt = kT + (size_t)b * Nn * CKn + (size_t)nt * 128 * CKn;
  f32x4 acc[8];
#pragma unroll
  for (int j = 0; j < 8; ++j) acc[j] = (f32x4)0.f;
  gemm64x128(A, Bt, CKn, CKn, CKn, As, Bs, acc);
  EPI_VARS;
  const float scale = 0.08838834764831845f;  // 128^-0.5
#pragma unroll
  for (int j = 0; j < 8; ++j)
#pragma unroll
    for (int rg = 0; rg < 4; ++rg) {
      int n = mt * 64 + wave * 16 + quad * 4 + rg;   // energy row
      int m = nt * 128 + j * 16 + l16;               // energy col
      energy[(size_t)b * Nn * Nn + (size_t)n * Nn + m] = acc[j][rg] * scale;
    }
}

// ---------- kernel 5: row softmax fp32 -> bf16 ----------
__global__ __launch_bounds__(256) void softmax_kernel(
    const float* __restrict__ energy, uint16_t* __restrict__ attn) {
  const size_t row = blockIdx.x;
  const float* e = energy + row * Nn;
  const int t = threadIdx.x;
  float v0[4];
  float mx = -3.4e38f;
#pragma unroll
  for (int i = 0; i < 4; ++i) { v0[i] = e[t + i * 256]; mx = fmaxf(mx, v0[i]); }
#pragma unroll
  for (int off = 32; off; off >>= 1) mx = fmaxf(mx, __shfl_xor(mx, off, 64));
  __shared__ float redm[4], reds[4];
  const int lane = t & 63, wave = t >> 6;
  if (lane == 0) redm[wave] = mx;
  __syncthreads();
  mx = fmaxf(fmaxf(redm[0], redm[1]), fmaxf(redm[2], redm[3]));
  float s = 0.f;
#pragma unroll
  for (int i = 0; i < 4; ++i) { v0[i] = __expf(v0[i] - mx); s += v0[i]; }
#pragma unroll
  for (int off = 32; off; off >>= 1) s += __shfl_xor(s, off, 64);
  if (lane == 0) reds[wave] = s;
  __syncthreads();
  s = reds[0] + reds[1] + reds[2] + reds[3];
  const float inv = 1.f / s;
#pragma unroll
  for (int i = 0; i < 4; ++i) attn[row * Nn + t + i * 256] = f2b(v0[i] * inv);
}

// ---------- kernel 6: osm = v * attn^T (NT, K=1024) -> fp32 [b][c][n] ----------
// grid 512 = 8 b * 8 mt * 8 nt
__global__ __launch_bounds__(256) void outg_kernel(
    const uint16_t* __restrict__ vm, const uint16_t* __restrict__ attn,
    float* __restrict__ osm) {
  __shared__ short As[2048], Bs[4096];
  const int bx = blockIdx.x;
  const int b = bx >> 6, r = bx & 63, mt = r >> 3, nt = r & 7;
  const uint16_t* A  = vm   + (size_t)b * Cn * Nn + (size_t)mt * 64 * Nn;
  const uint16_t* Bt = attn + (size_t)b * Nn * Nn + (size_t)nt * 128 * Nn;
  f32x4 acc[8];
#pragma unroll
  for (int j = 0; j < 8; ++j) acc[j] = (f32x4)0.f;
  gemm64x128(A, Bt, Nn, Nn, Nn, As, Bs, acc);
  EPI_VARS;
#pragma unroll
  for (int j = 0; j < 8; ++j)
#pragma unroll
    for (int rg = 0; rg < 4; ++rg) {
      int c = mt * 64 + wave * 16 + quad * 4 + rg;
      int n = nt * 128 + j * 16 + l16;
      osm[(size_t)b * Cn * Nn + (size_t)c * Nn + n] = acc[j][rg];
    }
}

// ---------- kernel 7: nearest 4x upsample + residual (streaming) ----------
// grid 65536 * 256: one float4 of out per thread
__global__ __launch_bounds__(256) void upsample_kernel(
    const float* __restrict__ osm, const float* __restrict__ c2,
    float* __restrict__ out) {
  const int t = blockIdx.x * 256 + threadIdx.x;        // < 2^24
  const int ww4 = t & 31;                              // float4 col (0..31)
  const int hh  = (t >> 5) & 127;
  const int cb  = t >> 12;                             // b*512 + c  (0..4095)
  const int n = (hh >> 2) * 32 + ww4;                  // pooled pixel
  const float val = osm[((size_t)cb << 10) + n];
  const size_t base = (((size_t)cb * Hn) + hh) * Hn + ww4 * 4;
  float4 t4 = *(const float4*)(c2 + base);
  t4.x += val; t4.y += val; t4.z += val; t4.w += val;
  *(float4*)(out + base) = t4;
}

// ---------- launch ----------
extern "C" void kernel_launch(void* const* d_in, const int* in_sizes, int n_in,
                              void* d_out, int out_size, void* d_ws, size_t ws_size,
                              hipStream_t stream) {
  const float* input = (const float*)d_in[0];
  const float* c2    = (const float*)d_in[1];
  const float* Wq    = (const float*)d_in[2];
  const float* bq    = (const float*)d_in[3];
  const float* Wk    = (const float*)d_in[4];
  const float* bk    = (const float*)d_in[5];
  const float* Wv    = (const float*)d_in[6];
  const float* bv    = (const float*)d_in[7];
  float* out = (float*)d_out;
  uint8_t* ws = (uint8_t*)d_ws;

  uint16_t* xT   = (uint16_t*)(ws + 0);            //  8 MB [8][1024][512]
  uint16_t* yT   = (uint16_t*)(ws + 8388608);      //  8 MB
  uint16_t* Wqb  = (uint16_t*)(ws + 16777216);     // 128 KB
  uint16_t* Wkb  = (uint16_t*)(ws + 16908288);     // 128 KB
  uint16_t* Wvb  = (uint16_t*)(ws + 17039360);     // 512 KB
  uint16_t* qT   = (uint16_t*)(ws + 17563648);     //  2 MB [8][1024][128]
  uint16_t* kT   = (uint16_t*)(ws + 19660800);     //  2 MB
  uint16_t* vm   = (uint16_t*)(ws + 21757952);     //  8 MB [8][512][1024]
  float*    eng  = (float*)   (ws + 30146560);     // 32 MB [8][1024][1024] fp32
  uint16_t* attn = (uint16_t*)(ws + 63700992);     // 16 MB [8][1024][1024] bf16
  float*    osm  = eng;                            // overlay: eng dead after softmax
  // total 80,478,208 bytes

  hipLaunchKernelGGL(wconv_kernel, dim3(1024), dim3(256), 0, stream,
                     Wq, Wk, Wv, Wqb, Wkb, Wvb);
  hipLaunchKernelGGL(pool_kernel, dim3(16, 32, 16), dim3(1024), 0, stream,
                     input, c2, xT, yT);
  hipLaunchKernelGGL(qkv_kernel, dim3(768), dim3(256), 0, stream,
                     Wqb, Wkb, Wvb, bq, bk, bv, xT, yT, qT, kT, vm);
  hipLaunchKernelGGL(energy_kernel, dim3(1024), dim3(256), 0, stream, qT, kT, eng);
  hipLaunchKernelGGL(softmax_kernel, dim3(8192), dim3(256), 0, stream, eng, attn);
  hipLaunchKernelGGL(outg_kernel, dim3(512), dim3(256), 0, stream, vm, attn, osm);
  hipLaunchKernelGGL(upsample_kernel, dim3(65536), dim3(256), 0, stream, osm, c2, out);
}